// Round 4
// baseline (182.679 us; speedup 1.0000x reference)
//
#include <hip/hip_runtime.h>
#include <hip/hip_bf16.h>

// ---------------------------------------------------------------------------
// NaiveFourierKANLayer as GEMM:  y = [cos|sin features][4096 x 32768] * W + b
// R4: A-fragments synthesized IN REGISTERS per lane (step-1 Chebyshev
// recurrence, seeds by angle doubling+rotation) -> no A-LDS traffic at all.
// B double-buffered via global_load_lds, ONE barrier/iter (drain covered by
// A-gen + MFMA span). bf16 MFMA 16x16x32, 128x128 tile, splitK=8, atomics.
// ---------------------------------------------------------------------------

typedef __attribute__((ext_vector_type(8))) short short8;
typedef __attribute__((ext_vector_type(4))) float f32x4;

#define SPLITK 8
#define ICHUNK (256 / SPLITK)   // 32 i's per block

// RNE f32->bf16 (convert kernel only; cost irrelevant there)
__device__ __forceinline__ unsigned short f2bf(float f) {
    unsigned u = __builtin_bit_cast(unsigned, f);
    u += 0x7fffu + ((u >> 16) & 1u);
    return (unsigned short)(u >> 16);
}
__device__ __forceinline__ unsigned pkbf16(float a, float b) {
    return (unsigned)f2bf(a) | ((unsigned)f2bf(b) << 16);
}

// fast round-half-up f32x2 -> packed bf16x2: 2 adds + 1 v_perm
__device__ __forceinline__ unsigned pk_rh(float a, float b) {
    unsigned ua = __builtin_bit_cast(unsigned, a) + 0x8000u;
    unsigned ub = __builtin_bit_cast(unsigned, b) + 0x8000u;
    return __builtin_amdgcn_perm(ub, ua, 0x07060302u);  // [ub.hi16 | ua.hi16]
}

// angle doubling: (c,s) -> (cos2a, sin2a)
__device__ __forceinline__ void dbl2(float c, float s, float& co, float& so) {
    float t = c + c;
    co = __builtin_fmaf(t, c, -1.f);
    so = t * s;
}
// angle addition: (c,s) rotated by (cr,sr)
__device__ __forceinline__ void rot2(float c, float s, float cr, float sr,
                                     float& co, float& so) {
    float t = s * sr;
    co = __builtin_fmaf(c, cr, -t);
    float u = s * cr;
    so = __builtin_fmaf(c, sr, u);
}

// 8 consecutive harmonics from seeds f_{-1}, f_0 with multiplier m1=2cos(x),
// packed low-to-high into an MFMA A-fragment (element j = harmonic n0+j).
__device__ __forceinline__ short8 chain8(float m1, float fm1, float f0) {
    unsigned r[4];
    float vp = fm1, v = f0;
    #pragma unroll
    for (int h = 0; h < 4; ++h) {
        float v1 = __builtin_fmaf(m1, v, -vp);
        r[h] = pk_rh(v, v1);
        float v2 = __builtin_fmaf(m1, v1, -v);
        vp = v1; v = v2;
    }
    uint4 u; u.x = r[0]; u.y = r[1]; u.z = r[2]; u.w = r[3];
    return __builtin_bit_cast(short8, u);
}

// async 16B global->LDS
__device__ __forceinline__ void async_load16(const void* g, void* l) {
    __builtin_amdgcn_global_load_lds(
        (const __attribute__((address_space(1))) unsigned int*)g,
        (__attribute__((address_space(3))) unsigned int*)l,
        16, 0, 0);
}

// out[b][o] = bias[o]
__global__ void init_out_kernel(float* __restrict__ out, const float* __restrict__ bias) {
    int tid = blockIdx.x * 256 + threadIdx.x;
    float4 b4 = ((const float4*)bias)[tid & 63];
    ((float4*)out)[tid] = b4;
}

// fc[t][o][i][g] fp32 -> ws2[(i*2+y)*2048 + gi] bf16 granules in LDS-image order
__global__ __launch_bounds__(256) void convert_coeffs2(
    const float* __restrict__ fc, unsigned short* __restrict__ ws2)
{
    __shared__ unsigned short lsh[256 * 72];
    const int bx = blockIdx.x;                 // i*2 + y
    const int i = bx >> 1, y = bx & 1;
    const int t = threadIdx.x;
    {
        const int tt = t >> 7, op = t & 127;
        const float4* src = (const float4*)(fc +
            ((((size_t)tt * 256) + y * 128 + op) * 256 + i) * 64);
        uint4* dst = (uint4*)(lsh + t * 72);
        #pragma unroll
        for (int q2 = 0; q2 < 8; ++q2) {
            float4 a = src[q2 * 2], b = src[q2 * 2 + 1];
            uint4 v;
            v.x = pkbf16(a.x, a.y); v.y = pkbf16(a.z, a.w);
            v.z = pkbf16(b.x, b.y); v.w = pkbf16(b.z, b.w);
            dst[q2] = v;
        }
    }
    __syncthreads();
    uint4* wdst = (uint4*)ws2 + (size_t)bx * 2048;
    #pragma unroll
    for (int rep = 0; rep < 8; ++rep) {
        int gi = rep * 256 + t;
        int sog = gi >> 6, ll = gi & 63;
        int s = sog >> 3, og = sog & 7;
        int op = og * 16 + (ll & 15);
        int k = s * 32 + ((ll >> 4) * 8);
        int tt = k >> 6, g0 = k & 63;
        wdst[gi] = *(const uint4*)(lsh + (tt * 128 + op) * 72 + g0);
    }
}

template <bool USE_WS>
__global__ __launch_bounds__(256, 2) void fkan_gemm(
    const float* __restrict__ x, const float* __restrict__ fc,
    const unsigned short* __restrict__ bws, float* __restrict__ out)
{
    __shared__ uint4 Bimg[2][2048];        // 64 KB: coeff image, double-buffered
    __shared__ float xs[ICHUNK][128];      // 16 KB: x[row][i] transposed

    const int t  = threadIdx.x;
    const int l  = t & 63;
    const int w  = t >> 6;
    const int wr = w >> 1, wc = w & 1;     // 2x2 waves of 64x64
    const int q  = l >> 4;                 // MFMA quad -> k offset 8q
    const int m  = l & 15;                 // MFMA row within 16
    const int rowBase = blockIdx.x * 128;
    const int by      = blockIdx.y;
    const int colBase = by * 128;
    const int iBase   = blockIdx.z * ICHUNK;
    const float q8f   = (float)(q * 8);

    f32x4 acc[4][4];
    #pragma unroll
    for (int a = 0; a < 4; ++a)
        #pragma unroll
        for (int b = 0; b < 4; ++b) acc[a][b] = (f32x4)0.0f;

    auto stageB = [&](int p, int i) {
        if (USE_WS) {
            const unsigned short* base = bws + ((size_t)(i * 2 + by) * 2048) * 8;
            #pragma unroll
            for (int cc = 0; cc < 8; ++cc) {
                int c = cc * 4 + w;
                async_load16(base + (size_t)(c * 64 + l) * 8, (void*)(&Bimg[p][c * 64]));
            }
        } else {
            #pragma unroll
            for (int gg = 0; gg < 8; ++gg) {
                int gi  = gg * 256 + t;
                int sog = gi >> 6, ll = gi & 63;
                int s = sog >> 3, ogb = sog & 7;
                int o = ogb * 16 + (ll & 15);
                int k = s * 32 + (ll >> 4) * 8;
                int tt = k >> 6, g = k & 63;
                const float4* p4 = (const float4*)(fc +
                    ((((size_t)tt * 256 + colBase + o) * 256 + i) * 64 + g));
                float4 a = p4[0], b = p4[1];
                uint4 v;
                v.x = pkbf16(a.x, a.y); v.y = pkbf16(a.z, a.w);
                v.z = pkbf16(b.x, b.y); v.w = pkbf16(b.z, b.w);
                Bimg[p][gi] = v;
            }
        }
    };

    // ---- preamble: stage B(iter0) + x tile, one barrier ----
    stageB(0, iBase);
    {
        int r = t >> 1, c0 = (t & 1) * 16;
        const float4* px = (const float4*)(x + (size_t)(rowBase + r) * 256 + iBase + c0);
        float4 v0 = px[0], v1 = px[1], v2 = px[2], v3 = px[3];
        float tmp[16] = { v0.x, v0.y, v0.z, v0.w, v1.x, v1.y, v1.z, v1.w,
                          v2.x, v2.y, v2.z, v2.w, v3.x, v3.y, v3.z, v3.w };
        #pragma unroll
        for (int j = 0; j < 16; ++j) xs[c0 + j][r] = tmp[j];
    }
    __syncthreads();

    #pragma unroll 1
    for (int ii = 0; ii < ICHUNK; ++ii) {
        const int p = ii & 1;

        // 1. B fragments of current buffer -> regs (16 ds_read_b128)
        short8 bF[4][4];
        #pragma unroll
        for (int s = 0; s < 4; ++s)
            #pragma unroll
            for (int cf = 0; cf < 4; ++cf)
                bF[s][cf] = __builtin_bit_cast(short8,
                    Bimg[p][(s * 8 + wc * 4 + cf) * 64 + l]);

        // 2. async-stage next B into the other buffer
        if (ii + 1 < ICHUNK) stageB(p ^ 1, iBase + ii + 1);

        // 3. synthesize A fragments in registers (covers load + ds_read latency)
        short8 aF[4][4];   // [rf][s]
        #pragma unroll
        for (int rf = 0; rf < 4; ++rf) {
            float xv = xs[ii][wr * 64 + rf * 16 + m];
            float s1, c1;
            __sincosf(xv, &s1, &c1);
            const float m1 = c1 + c1;
            float c2, s2, c4, s4, c8, s8, c16, s16, c32, s32;
            dbl2(c1, s1, c2, s2);
            dbl2(c2, s2, c4, s4);
            dbl2(c4, s4, c8, s8);
            dbl2(c8, s8, c16, s16);
            dbl2(c16, s16, c32, s32);
            float c24, s24;
            rot2(c16, s16, c8, s8, c24, s24);
            // (cq,sq) = (cos(8q x), sin(8q x))
            float cq = (q == 0) ? 1.f : (q == 1) ? c8 : (q == 2) ? c16 : c24;
            float sq = (q == 0) ? 0.f : (q == 1) ? s8 : (q == 2) ? s16 : s24;
            float cq1, sq1, cB, sB, cB1, sB1;
            rot2(cq, sq, c1, s1, cq1, sq1);     // 8q+1
            rot2(cq, sq, c32, s32, cB, sB);     // 8q+32
            rot2(cB, sB, c1, s1, cB1, sB1);     // 8q+33
            aF[rf][0] = chain8(m1, cq, cq1);    // cos, freq 8q+1..8q+8
            aF[rf][1] = chain8(m1, cB, cB1);    // cos, freq 8q+33..
            aF[rf][2] = chain8(m1, sq, sq1);    // sin, freq 8q+1..
            aF[rf][3] = chain8(m1, sB, sB1);    // sin, freq 8q+33..
        }

        // 4. MFMA
        #pragma unroll
        for (int s = 0; s < 4; ++s)
            #pragma unroll
            for (int rf = 0; rf < 4; ++rf)
                #pragma unroll
                for (int cf = 0; cf < 4; ++cf)
                    acc[rf][cf] = __builtin_amdgcn_mfma_f32_16x16x32_bf16(
                        aF[rf][s], bF[s][cf], acc[rf][cf], 0, 0, 0);

        // 5. one barrier: vmcnt drain covered by steps 3-4
        __syncthreads();
    }

    // epilogue: C/D layout col=l&15, row=(l>>4)*4+e ; splitK via atomics
    const int lr = (l >> 4) * 4;
    const int r0 = rowBase + wr * 64 + lr;
    const int c0 = colBase + wc * 64 + m;
    #pragma unroll
    for (int rf = 0; rf < 4; ++rf)
        #pragma unroll
        for (int cf = 0; cf < 4; ++cf)
            #pragma unroll
            for (int e = 0; e < 4; ++e)
                atomicAdd(out + (size_t)(r0 + rf * 16 + e) * 256 + (c0 + cf * 16),
                          acc[rf][cf][e]);
}

extern "C" void kernel_launch(void* const* d_in, const int* in_sizes, int n_in,
                              void* d_out, int out_size, void* d_ws, size_t ws_size,
                              hipStream_t stream) {
    const float* x    = (const float*)d_in[0];
    const float* fc   = (const float*)d_in[1];
    const float* bias = (const float*)d_in[2];
    float* out = (float*)d_out;
    unsigned short* bws = (unsigned short*)d_ws;

    hipLaunchKernelGGL(init_out_kernel, dim3(1024), dim3(256), 0, stream, out, bias);

    const size_t wsNeed = (size_t)512 * 2048 * 16;   // 16.78 MB image-order coeffs
    if (ws_size >= wsNeed) {
        hipLaunchKernelGGL(convert_coeffs2, dim3(512), dim3(256), 0, stream, fc, bws);
        hipLaunchKernelGGL((fkan_gemm<true>), dim3(32, 2, SPLITK), dim3(256), 0, stream,
                           x, fc, bws, out);
    } else {
        hipLaunchKernelGGL((fkan_gemm<false>), dim3(32, 2, SPLITK), dim3(256), 0, stream,
                           x, fc, bws, out);
    }
}

// Round 5
// 181.494 us; speedup vs baseline: 1.0065x; 1.0065x over previous
//
#include <hip/hip_runtime.h>
#include <hip/hip_bf16.h>

// ---------------------------------------------------------------------------
// NaiveFourierKANLayer as GEMM:  y = [cos|sin features][4096 x 32768] * W + b
// R5: R4 structure (A synthesized in registers, B double-buffered via
// global_load_lds, one barrier/iter) with:
//   - hardware v_sin/v_cos (revolutions) instead of __sincosf
//   - v_cvt_pk_bf16_f32 packing when available
//   - single-pass coalesced convert kernel (no LDS, 16B granule per thread)
// ---------------------------------------------------------------------------

typedef __attribute__((ext_vector_type(8))) short short8;
typedef __attribute__((ext_vector_type(4))) float f32x4;

#define SPLITK 8
#define ICHUNK (256 / SPLITK)   // 32 i's per block

#define INV2PI 0.15915494309189535f

// ---- bf16x2 pack: v_cvt_pk_bf16_f32 if available, else manual ----
#if __has_builtin(__builtin_amdgcn_cvt_pk_bf16_f32)
typedef __attribute__((ext_vector_type(2))) __bf16 bf16x2_t;
__device__ __forceinline__ unsigned pkbf16(float a, float b) {
    bf16x2_t v = __builtin_amdgcn_cvt_pk_bf16_f32(a, b);
    return __builtin_bit_cast(unsigned, v);
}
#else
__device__ __forceinline__ unsigned pkbf16(float a, float b) {
    unsigned ua = __builtin_bit_cast(unsigned, a) + 0x8000u;
    unsigned ub = __builtin_bit_cast(unsigned, b) + 0x8000u;
    return __builtin_amdgcn_perm(ub, ua, 0x07060302u);  // [b.hi16 | a.hi16]
}
#endif

// angle doubling: (c,s) -> (cos2a, sin2a)
__device__ __forceinline__ void dbl2(float c, float s, float& co, float& so) {
    float t = c + c;
    co = __builtin_fmaf(t, c, -1.f);
    so = t * s;
}
// angle addition: (c,s) rotated by (cr,sr)
__device__ __forceinline__ void rot2(float c, float s, float cr, float sr,
                                     float& co, float& so) {
    float t = s * sr;
    co = __builtin_fmaf(c, cr, -t);
    float u = s * cr;
    so = __builtin_fmaf(c, sr, u);
}

// 8 consecutive harmonics from seeds f_{-1}, f_0 with multiplier m1=2cos(x),
// packed low-to-high into an MFMA A-fragment (element j = harmonic n0+j).
__device__ __forceinline__ short8 chain8(float m1, float fm1, float f0) {
    unsigned r[4];
    float vp = fm1, v = f0;
    #pragma unroll
    for (int h = 0; h < 4; ++h) {
        float v1 = __builtin_fmaf(m1, v, -vp);
        r[h] = pkbf16(v, v1);
        float v2 = __builtin_fmaf(m1, v1, -v);
        vp = v1; v = v2;
    }
    uint4 u; u.x = r[0]; u.y = r[1]; u.z = r[2]; u.w = r[3];
    return __builtin_bit_cast(short8, u);
}

// async 16B global->LDS
__device__ __forceinline__ void async_load16(const void* g, void* l) {
    __builtin_amdgcn_global_load_lds(
        (const __attribute__((address_space(1))) unsigned int*)g,
        (__attribute__((address_space(3))) unsigned int*)l,
        16, 0, 0);
}

// out[b][o] = bias[o]
__global__ void init_out_kernel(float* __restrict__ out, const float* __restrict__ bias) {
    int tid = blockIdx.x * 256 + threadIdx.x;
    float4 b4 = ((const float4*)bias)[tid & 63];
    ((float4*)out)[tid] = b4;
}

// Single-pass convert: one 16B image granule per thread.
//   flat = bx*2048 + gi ; bx = i*2+y ; gi = (s*8+og)*64 + ll
//   op = og*16 + (ll&15); k = s*32 + (ll>>4)*8; tt = k>>6; g0 = k&63
//   ws2 granule <- bf16(fc[tt][y*128+op][i][g0..g0+7])   (32B contiguous read)
__global__ __launch_bounds__(256) void convert_coeffs3(
    const float* __restrict__ fc, unsigned short* __restrict__ ws2)
{
    unsigned flat = blockIdx.x * 256 + threadIdx.x;   // 0 .. 2^20-1
    unsigned bx = flat >> 11, gi = flat & 2047;
    unsigned i = bx >> 1, y = bx & 1;
    unsigned sog = gi >> 6, ll = gi & 63;
    unsigned s = sog >> 3, og = sog & 7;
    unsigned op = og * 16 + (ll & 15);
    unsigned k = s * 32 + ((ll >> 4) * 8);
    unsigned tt = k >> 6, g0 = k & 63;
    const float4* src = (const float4*)(fc +
        ((((size_t)tt * 256 + y * 128 + op) * 256 + i) * 64 + g0));
    float4 a = src[0], b = src[1];
    uint4 v;
    v.x = pkbf16(a.x, a.y); v.y = pkbf16(a.z, a.w);
    v.z = pkbf16(b.x, b.y); v.w = pkbf16(b.z, b.w);
    ((uint4*)ws2)[flat] = v;
}

template <bool USE_WS>
__global__ __launch_bounds__(256, 2) void fkan_gemm(
    const float* __restrict__ x, const float* __restrict__ fc,
    const unsigned short* __restrict__ bws, float* __restrict__ out)
{
    __shared__ uint4 Bimg[2][2048];        // 64 KB: coeff image, double-buffered
    __shared__ float xs[ICHUNK][128];      // 16 KB: x[row][i] transposed

    const int t  = threadIdx.x;
    const int l  = t & 63;
    const int w  = t >> 6;
    const int wr = w >> 1, wc = w & 1;     // 2x2 waves of 64x64
    const int q  = l >> 4;                 // MFMA quad -> k offset 8q
    const int m  = l & 15;                 // MFMA row within 16
    const int rowBase = blockIdx.x * 128;
    const int by      = blockIdx.y;
    const int colBase = by * 128;
    const int iBase   = blockIdx.z * ICHUNK;

    f32x4 acc[4][4];
    #pragma unroll
    for (int a = 0; a < 4; ++a)
        #pragma unroll
        for (int b = 0; b < 4; ++b) acc[a][b] = (f32x4)0.0f;

    auto stageB = [&](int p, int i) {
        if (USE_WS) {
            const unsigned short* base = bws + ((size_t)(i * 2 + by) * 2048) * 8;
            #pragma unroll
            for (int cc = 0; cc < 8; ++cc) {
                int c = cc * 4 + w;
                async_load16(base + (size_t)(c * 64 + l) * 8, (void*)(&Bimg[p][c * 64]));
            }
        } else {
            #pragma unroll
            for (int gg = 0; gg < 8; ++gg) {
                int gi  = gg * 256 + t;
                int sog = gi >> 6, ll = gi & 63;
                int s = sog >> 3, ogb = sog & 7;
                int o = ogb * 16 + (ll & 15);
                int k = s * 32 + (ll >> 4) * 8;
                int tt = k >> 6, g = k & 63;
                const float4* p4 = (const float4*)(fc +
                    ((((size_t)tt * 256 + colBase + o) * 256 + i) * 64 + g));
                float4 a = p4[0], b = p4[1];
                uint4 v;
                v.x = pkbf16(a.x, a.y); v.y = pkbf16(a.z, a.w);
                v.z = pkbf16(b.x, b.y); v.w = pkbf16(b.z, b.w);
                Bimg[p][gi] = v;
            }
        }
    };

    // ---- preamble: stage B(iter0) + x tile, one barrier ----
    stageB(0, iBase);
    {
        int r = t >> 1, c0 = (t & 1) * 16;
        const float4* px = (const float4*)(x + (size_t)(rowBase + r) * 256 + iBase + c0);
        float4 v0 = px[0], v1 = px[1], v2 = px[2], v3 = px[3];
        float tmp[16] = { v0.x, v0.y, v0.z, v0.w, v1.x, v1.y, v1.z, v1.w,
                          v2.x, v2.y, v2.z, v2.w, v3.x, v3.y, v3.z, v3.w };
        #pragma unroll
        for (int j = 0; j < 16; ++j) xs[c0 + j][r] = tmp[j];
    }
    __syncthreads();

    #pragma unroll 1
    for (int ii = 0; ii < ICHUNK; ++ii) {
        const int p = ii & 1;

        // 1. B fragments of current buffer -> regs (16 ds_read_b128)
        short8 bF[4][4];
        #pragma unroll
        for (int s = 0; s < 4; ++s)
            #pragma unroll
            for (int cf = 0; cf < 4; ++cf)
                bF[s][cf] = __builtin_bit_cast(short8,
                    Bimg[p][(s * 8 + wc * 4 + cf) * 64 + l]);

        // 2. async-stage next B into the other buffer
        if (ii + 1 < ICHUNK) stageB(p ^ 1, iBase + ii + 1);

        // 3. synthesize A fragments in registers (HW v_sin/v_cos seeds)
        short8 aF[4][4];   // [rf][s]
        #pragma unroll
        for (int rf = 0; rf < 4; ++rf) {
            float xv = xs[ii][wr * 64 + rf * 16 + m];
            float rev = xv * INV2PI;
            float s1 = __builtin_amdgcn_sinf(rev);
            float c1 = __builtin_amdgcn_cosf(rev);
            const float m1 = c1 + c1;
            float c2, s2, c4, s4, c8, s8, c16, s16, c32, s32;
            dbl2(c1, s1, c2, s2);
            dbl2(c2, s2, c4, s4);
            dbl2(c4, s4, c8, s8);
            dbl2(c8, s8, c16, s16);
            dbl2(c16, s16, c32, s32);
            float c24, s24;
            rot2(c16, s16, c8, s8, c24, s24);
            // (cq,sq) = (cos(8q x), sin(8q x))
            float cq = (q == 0) ? 1.f : (q == 1) ? c8 : (q == 2) ? c16 : c24;
            float sq = (q == 0) ? 0.f : (q == 1) ? s8 : (q == 2) ? s16 : s24;
            float cq1, sq1, cB, sB, cB1, sB1;
            rot2(cq, sq, c1, s1, cq1, sq1);     // 8q+1
            rot2(cq, sq, c32, s32, cB, sB);     // 8q+32
            rot2(cB, sB, c1, s1, cB1, sB1);     // 8q+33
            aF[rf][0] = chain8(m1, cq, cq1);    // cos, freq 8q+1..8q+8
            aF[rf][1] = chain8(m1, cB, cB1);    // cos, freq 8q+33..
            aF[rf][2] = chain8(m1, sq, sq1);    // sin, freq 8q+1..
            aF[rf][3] = chain8(m1, sB, sB1);    // sin, freq 8q+33..
        }

        // 4. MFMA
        #pragma unroll
        for (int s = 0; s < 4; ++s)
            #pragma unroll
            for (int rf = 0; rf < 4; ++rf)
                #pragma unroll
                for (int cf = 0; cf < 4; ++cf)
                    acc[rf][cf] = __builtin_amdgcn_mfma_f32_16x16x32_bf16(
                        aF[rf][s], bF[s][cf], acc[rf][cf], 0, 0, 0);

        // 5. one barrier: vmcnt drain covered by steps 3-4
        __syncthreads();
    }

    // epilogue: C/D layout col=l&15, row=(l>>4)*4+e ; splitK via atomics
    const int lr = (l >> 4) * 4;
    const int r0 = rowBase + wr * 64 + lr;
    const int c0 = colBase + wc * 64 + m;
    #pragma unroll
    for (int rf = 0; rf < 4; ++rf)
        #pragma unroll
        for (int cf = 0; cf < 4; ++cf)
            #pragma unroll
            for (int e = 0; e < 4; ++e)
                atomicAdd(out + (size_t)(r0 + rf * 16 + e) * 256 + (c0 + cf * 16),
                          acc[rf][cf][e]);
}

extern "C" void kernel_launch(void* const* d_in, const int* in_sizes, int n_in,
                              void* d_out, int out_size, void* d_ws, size_t ws_size,
                              hipStream_t stream) {
    const float* x    = (const float*)d_in[0];
    const float* fc   = (const float*)d_in[1];
    const float* bias = (const float*)d_in[2];
    float* out = (float*)d_out;
    unsigned short* bws = (unsigned short*)d_ws;

    hipLaunchKernelGGL(init_out_kernel, dim3(1024), dim3(256), 0, stream, out, bias);

    const size_t wsNeed = (size_t)512 * 2048 * 16;   // 16.78 MB image-order coeffs
    if (ws_size >= wsNeed) {
        hipLaunchKernelGGL(convert_coeffs3, dim3(4096), dim3(256), 0, stream, fc, bws);
        hipLaunchKernelGGL((fkan_gemm<true>), dim3(32, 2, SPLITK), dim3(256), 0, stream,
                           x, fc, bws, out);
    } else {
        hipLaunchKernelGGL((fkan_gemm<false>), dim3(32, 2, SPLITK), dim3(256), 0, stream,
                           x, fc, bws, out);
    }
}